// Round 2
// baseline (2273.186 us; speedup 1.0000x reference)
//
#include <hip/hip_runtime.h>
#include <hip/hip_bf16.h>

// Bahdanau additive attention, MI355X. B=32, S=2048, E=D=1024. M = B*S = 65536.
// scores[m] = v . tanh(enc[m,:] @ w1 + qq[b]),  qq[b] = dec[b] @ w2 + b2 + b1
// (bv dropped: softmax-invariant). attn = softmax_s(scores); context[b] = attn[b,:] @ enc[b,:,:]
//
// Round-7 structure: A-resident GEMM, K-CHUNKED TO 64 KiB for 2 blocks/CU.
// Round-6 (128 KiB A-panel, 1 barrier) was occupancy-starved: 1 block/CU =
// 2 waves/SIMD, latency-bound (MfmaUtil 27%, Occupancy 21%, HBM 9%).
// Now each block owns 64 m-rows; A is staged in TWO 64-row x 512-k chunks
// (64 KiB LDS, single-buffered, 3 barriers/block). 2 blocks/CU = 4 waves/SIMD;
// one block's stage overlaps the other's MFMA phase (m114 wave-level overlap).
//   - w1 pre-packed FRAGMENT-LINEAR: frag(kt,nt) = 1 KiB, lane l holds
//     B[n=nt*16+(l&15)][k=kt*32+(l>>4)*8+j] as 16 contiguous bytes ->
//     one coalesced global_load_dwordx4 per frag, L2-resident (2 MB),
//     double-buffered one k32-step ahead in registers. No B LDS.
//   - 8 waves x n-strip 128: per k32-step 4 ds_read (A) + 8 L2 loads (B)
//     + 32 MFMA.
// LDS swizzle: row = 1024 B = 64 chunks of 16 B; logical chunk c stored at
// (c&~7)|((c^(r&7))&7). ds_write staging (8 lanes cover one 128 B window)
// and ds_read fragment reads both spread across bank groups.

typedef __attribute__((ext_vector_type(8))) short short8;   // 8 bf16 (4 VGPRs)
typedef __attribute__((ext_vector_type(4))) float f32x4;    // MFMA acc

#define M_TOTAL 65536
#define KDIM    1024

// pack two fp32 -> two bf16 (round-half-up) in one dword: 2 adds + 1 v_perm
static __device__ inline unsigned int pk2h(float a, float b) {
    unsigned int ua = __builtin_bit_cast(unsigned int, a) + 0x8000u;
    unsigned int ub = __builtin_bit_cast(unsigned int, b) + 0x8000u;
    return __builtin_amdgcn_perm(ub, ua, 0x07060302u);
}

// ---- w1 [d=k][e=n] fp32 -> fragment-linear bf16 image ----
// frag index = kt*64 + nt  (kt = k/32 in 0..31, nt = n/16 in 0..63)
// within frag: lane l, elem j = w1[kt*32 + (l>>4)*8 + j][nt*16 + (l&15)]
// -> 1 KiB per frag, each lane's 8 bf16 contiguous (one dwordx4 per load).
__global__ __launch_bounds__(64) void pack_w1(const float* __restrict__ w1,
                                              unsigned short* __restrict__ w1p) {
    const int nt = blockIdx.x;       // 0..63
    const int kt = blockIdx.y;       // 0..31
    const int l  = threadIdx.x;      // 0..63
    const int n  = nt * 16 + (l & 15);
    const int kb = kt * 32 + (l >> 4) * 8;
    const float* s = w1 + (size_t)kb * 1024 + n;
    uint4 wv;
    wv.x = pk2h(s[0],    s[1024]);
    wv.y = pk2h(s[2048], s[3072]);
    wv.z = pk2h(s[4096], s[5120]);
    wv.w = pk2h(s[6144], s[7168]);
    *reinterpret_cast<uint4*>(w1p + (((size_t)(kt * 64 + nt)) << 9) + (l << 3)) = wv;
}

// ---- qq[b][e] += partial of b1+b2 + dec[b]@w2, split-k x4 ----
__global__ __launch_bounds__(256) void qq_kern(const float* __restrict__ dec,
                                               const float* __restrict__ w2,
                                               const float* __restrict__ b1,
                                               const float* __restrict__ b2,
                                               float* __restrict__ qq) {
    const int b = blockIdx.y;
    const int e = blockIdx.x * 256 + threadIdx.x;
    const int d0 = blockIdx.z * 256;
    const float* db = dec + b * 1024;
    float acc = (blockIdx.z == 0) ? (b1[e] + b2[e]) : 0.f;
#pragma unroll 8
    for (int d = d0; d < d0 + 256; d++)
        acc = fmaf(db[d], w2[d * 1024 + e], acc);
    atomicAdd(&qq[b * 1024 + e], acc);
}

// ---- fused GEMM: A-panel resident in LDS (2 K-chunks), B streamed L2->regs ----
__global__ __launch_bounds__(512, 4) void score_gemm(const float* __restrict__ enc,
                                                     const unsigned short* __restrict__ w1p,
                                                     const float* __restrict__ qq,
                                                     const float* __restrict__ vvec,
                                                     float* __restrict__ scores) {
    __shared__ __align__(16) unsigned short As[64 * 512];   // 64 KiB -> 2 blocks/CU

    const int m0 = blockIdx.x << 6;       // 64 m-rows per block, 1024 blocks
    const int b = m0 >> 11;
    const int tid = threadIdx.x;
    const int wid = tid >> 6;             // 0..7, n-strip = wid*128
    const int lane = tid & 63;
    const int quad = lane >> 4, lc = lane & 15;

    // staging geometry: thread tid -> row sr = tid>>3, chunk-low sc8 = tid&7.
    // per chunk kc: 8 windows w of 128 B per row; chunk c = w*8+sc8 stored
    // at w*8 + (sc8 ^ (sr&7)).
    const int sr  = tid >> 3;
    const int sc8 = tid & 7;
    const int sw8 = sc8 ^ (sr & 7);
    const float* srcbase = enc + (size_t)(m0 + sr) * 1024 + (sc8 << 3);
    unsigned short* dstbase = As + (sr << 9) + (sw8 << 3);

    f32x4 acc[4][8];
#pragma unroll
    for (int mi = 0; mi < 4; mi++)
#pragma unroll
        for (int ni = 0; ni < 8; ni++)
            acc[mi][ni] = (f32x4){0.f, 0.f, 0.f, 0.f};

    // B fragment stream base for this wave: frags (kt*64 + wid*8 + ni)
    // short offset = kt*32768 + wid*4096 + ni*512 + lane*8
    const unsigned short* bb = w1p + ((size_t)wid << 12) + (lane << 3);

    short8 bA[8], bB[8];
#pragma unroll
    for (int ni = 0; ni < 8; ni++)
        bA[ni] = *reinterpret_cast<const short8*>(bb + ni * 512);   // kt = 0

    for (int kc = 0; kc < 2; ++kc) {
        if (kc) __syncthreads();          // prior chunk's LDS reads done
        // ---- stage A chunk kc: enc[m0..m0+64) x k[kc*512 .. kc*512+512) ----
        {
            const float* s0 = srcbase + (kc << 9);
#pragma unroll
            for (int w = 0; w < 8; w++) {
                const float* s = s0 + (w << 6);
                float4 f0 = *reinterpret_cast<const float4*>(s);
                float4 f1 = *reinterpret_cast<const float4*>(s + 4);
                uint4 pv;
                pv.x = pk2h(f0.x, f0.y);
                pv.y = pk2h(f0.z, f0.w);
                pv.z = pk2h(f1.x, f1.y);
                pv.w = pk2h(f1.z, f1.w);
                *reinterpret_cast<uint4*>(dstbase + (w << 6)) = pv;
            }
        }
        __syncthreads();                  // chunk visible to all waves

        for (int ktl = 0; ktl < 16; ktl += 2) {
            const int kt = (kc << 4) + ktl;     // global k32-step
            // prefetch kt+1 into bB (L2 latency hides under this step's MFMAs)
#pragma unroll
            for (int ni = 0; ni < 8; ni++)
                bB[ni] = *reinterpret_cast<const short8*>(bb + (kt + 1) * 32768 + ni * 512);

            short8 af[4];
            {
                const int c = ktl * 4 + quad;               // chunk within LDS image
                const int off = ((c & ~7) | ((c ^ lc) & 7)) << 3;
#pragma unroll
                for (int mi = 0; mi < 4; mi++)
                    af[mi] = *reinterpret_cast<const short8*>(&As[((mi * 16 + lc) << 9) + off]);
            }
            __builtin_amdgcn_s_setprio(1);
#pragma unroll
            for (int mi = 0; mi < 4; mi++)
#pragma unroll
                for (int ni = 0; ni < 8; ni++)
                    acc[mi][ni] = __builtin_amdgcn_mfma_f32_16x16x32_bf16(af[mi], bA[ni], acc[mi][ni], 0, 0, 0);
            __builtin_amdgcn_s_setprio(0);

            // prefetch kt+2 into bA
            if (kt < 30) {
#pragma unroll
                for (int ni = 0; ni < 8; ni++)
                    bA[ni] = *reinterpret_cast<const short8*>(bb + (kt + 2) * 32768 + ni * 512);
            }
            {
                const int c = ktl * 4 + 4 + quad;
                const int off = ((c & ~7) | ((c ^ lc) & 7)) << 3;
#pragma unroll
                for (int mi = 0; mi < 4; mi++)
                    af[mi] = *reinterpret_cast<const short8*>(&As[((mi * 16 + lc) << 9) + off]);
            }
            __builtin_amdgcn_s_setprio(1);
#pragma unroll
            for (int mi = 0; mi < 4; mi++)
#pragma unroll
                for (int ni = 0; ni < 8; ni++)
                    acc[mi][ni] = __builtin_amdgcn_mfma_f32_16x16x32_bf16(af[mi], bB[ni], acc[mi][ni], 0, 0, 0);
            __builtin_amdgcn_s_setprio(0);
        }
    }

    // ---- epilogue: tanh(C + qq)*v, reduce over this wave's 128 n ----
    // acc[mi][ni][r] = C[m = mi*16 + quad*4 + r][n = wid*128 + ni*16 + lc]
    const float* qb = qq + (b << 10) + (wid << 7) + lc;
    const float* vb = vvec + (wid << 7) + lc;
    float qn[8], vn[8];
#pragma unroll
    for (int ni = 0; ni < 8; ni++) {
        qn[ni] = qb[ni << 4];
        vn[ni] = vb[ni << 4];
    }
    float red[16];
#pragma unroll
    for (int mi = 0; mi < 4; mi++) {
#pragma unroll
        for (int r = 0; r < 4; r++) {
            float ssum = 0.f;
#pragma unroll
            for (int ni = 0; ni < 8; ni++) {
                float x = acc[mi][ni][r] + qn[ni];
                float e = __expf(2.0f * x);          // overflow-safe tanh
                float th = 1.0f - 2.0f / (e + 1.0f);
                ssum = fmaf(th, vn[ni], ssum);
            }
            float t = ssum;
            t += __shfl_xor(t, 1);
            t += __shfl_xor(t, 2);
            t += __shfl_xor(t, 4);
            t += __shfl_xor(t, 8);
            red[mi * 4 + r] = t;
        }
    }
    float myv = red[0];
#pragma unroll
    for (int i = 1; i < 16; i++)
        if (lc == i) myv = red[i];
    // lane (quad,lc) owns m = (lc>>2)*16 + quad*4 + (lc&3); 8 waves atomic-add
    atomicAdd(scores + m0 + (lc >> 2) * 16 + quad * 4 + (lc & 3), myv);
}

// ---- softmax over s (2048) per batch ----
__global__ __launch_bounds__(256) void softmax_kern(const float* __restrict__ scores,
                                                    float* __restrict__ attn) {
    const int b = blockIdx.x;
    const int tid = threadIdx.x;
    const int wid = tid >> 6, lane = tid & 63;
    const float* s = scores + b * 2048;
    float x[8];
    float m = -1e30f;
#pragma unroll
    for (int i = 0; i < 8; i++) {
        x[i] = s[tid + i * 256];
        m = fmaxf(m, x[i]);
    }
    for (int off = 1; off < 64; off <<= 1) m = fmaxf(m, __shfl_xor(m, off));
    __shared__ float redm[4];
    if (lane == 0) redm[wid] = m;
    __syncthreads();
    m = fmaxf(fmaxf(redm[0], redm[1]), fmaxf(redm[2], redm[3]));
    float sum = 0.f;
#pragma unroll
    for (int i = 0; i < 8; i++) {
        x[i] = __expf(x[i] - m);
        sum += x[i];
    }
    for (int off = 1; off < 64; off <<= 1) sum += __shfl_xor(sum, off);
    __shared__ float reds[4];
    if (lane == 0) reds[wid] = sum;
    __syncthreads();
    sum = reds[0] + reds[1] + reds[2] + reds[3];
    const float inv = 1.0f / sum;
#pragma unroll
    for (int i = 0; i < 8; i++) attn[b * 2048 + tid + i * 256] = x[i] * inv;
}

// ---- context[b][e] = sum_s attn[b][s] * enc[b][s][e] ----
__global__ __launch_bounds__(256) void ctx_kern(const float* __restrict__ attn,
                                                const float* __restrict__ enc,
                                                float* __restrict__ out) {
    const int b = blockIdx.y;
    const int sc = blockIdx.x;    // 32 chunks x 64 s
    const int tid = threadIdx.x;
    const float* ab = attn + b * 2048 + sc * 64;
    const float* eb = enc + ((size_t)b * 2048 + sc * 64) * 1024 + tid * 4;
    float4 acc = {0.f, 0.f, 0.f, 0.f};
#pragma unroll 16
    for (int s = 0; s < 64; s++) {
        float w = ab[s];
        float4 ev = *reinterpret_cast<const float4*>(eb + (size_t)s * 1024);
        acc.x = fmaf(w, ev.x, acc.x);
        acc.y = fmaf(w, ev.y, acc.y);
        acc.z = fmaf(w, ev.z, acc.z);
        acc.w = fmaf(w, ev.w, acc.w);
    }
    float* op = out + b * 1024 + tid * 4;
    atomicAdd(op + 0, acc.x);
    atomicAdd(op + 1, acc.y);
    atomicAdd(op + 2, acc.z);
    atomicAdd(op + 3, acc.w);
}

extern "C" void kernel_launch(void* const* d_in, const int* in_sizes, int n_in,
                              void* d_out, int out_size, void* d_ws, size_t ws_size,
                              hipStream_t stream) {
    const float* enc = (const float*)d_in[0];  // 32*2048*1024
    const float* dec = (const float*)d_in[1];  // 32*1*1024
    const float* w1  = (const float*)d_in[2];  // 1024*1024
    const float* b1  = (const float*)d_in[3];  // 1024
    const float* w2  = (const float*)d_in[4];  // 1024*1024
    const float* b2  = (const float*)d_in[5];  // 1024
    const float* v   = (const float*)d_in[6];  // 1024
    // d_in[7] = bv, softmax-invariant, unused
    float* out = (float*)d_out;                // 32*1024

    char* ws = (char*)d_ws;
    unsigned short* w1p = (unsigned short*)ws;                 // 2 MB
    float* qq     = (float*)(ws + (2u << 20));                 // 128 KB
    float* scores = (float*)(ws + (2u << 20) + (128u << 10));  // 256 KB
    float* attn   = scores + M_TOTAL;                          // 256 KB
    // total ws need: ~2.65 MB (small footprint keeps enc warm in L3)

    hipMemsetAsync(qq, 0, (128u << 10) + M_TOTAL * sizeof(float), stream);
    hipMemsetAsync(out, 0, 32 * 1024 * sizeof(float), stream);

    pack_w1<<<dim3(64, 32), 64, 0, stream>>>(w1, w1p);
    qq_kern<<<dim3(4, 32, 4), 256, 0, stream>>>(dec, w2, b1, b2, qq);
    score_gemm<<<1024, 512, 0, stream>>>(enc, w1p, qq, v, scores);
    softmax_kern<<<32, 256, 0, stream>>>(scores, attn);
    ctx_kern<<<dim3(32, 32), 256, 0, stream>>>(attn, enc, out);
}

// Round 3
// 530.283 us; speedup vs baseline: 4.2867x; 4.2867x over previous
//
#include <hip/hip_runtime.h>
#include <hip/hip_bf16.h>

// Bahdanau additive attention, MI355X. B=32, S=2048, E=D=1024. M = B*S = 65536.
// scores[m] = v . tanh(enc[m,:] @ w1 + qq[b]),  qq[b] = dec[b] @ w2 + b2 + b1
// (bv dropped: softmax-invariant). attn = softmax_s(scores); context[b] = attn[b,:] @ enc[b,:,:]
//
// Round-8 structure: A-resident GEMM with CHUNKED DOUBLE-BUFFERED staging.
// Lesson from round-7 (2273 us): at 112 VGPR + 128 acc-AGPR = 240 regs/wave
// (unified file), 2 waves/SIMD is a HARD register ceiling; launch_bounds(512,4)
// spilled the accumulators (9 GB scratch traffic). Occupancy stays 2/SIMD.
// Therefore overlap must come from INTRA-wave pipelining, not more waves:
//   - A panel (64 m-rows x K=1024) staged in 4 chunks of K=256 (2 x 32 KiB
//     LDS, double-buffered). Chunk c+1's fp32 loads are issued at the start
//     of chunk c (held in 4 float4 regs, two sub-batches), converted and
//     ds_written at mid/end of chunk c, one barrier per chunk. Staging
//     latency hides under ~620-1240 cyc of MFMA per chunk (T14 split).
//   - w1 pre-packed FRAGMENT-LINEAR: frag(kt,nt) = 1 KiB; B operand loads are
//     single coalesced global_load_dwordx4 from L2 (2 MB resident),
//     double-buffered one k32-step ahead in registers. No B LDS.
//   - 8 waves x n-strip 128: per k32-step 4 ds_read (A) + 8 L2 loads (B)
//     + 32 MFMA.
// LDS swizzle per 32-KiB buffer: row = 512 B = 32 chunks of 16 B; logical
// chunk c stored at (c&~7)|((c^(r&7))&7). Same family verified 0-critical
// conflict in rounds 2-7 (4.2M cyc ~ 3%, negligible).
//
// ctx path rewritten atomic-free: ctx_part writes per-(schunk,b) partials to
// ws (4 MB), ctx_reduce sums 32 partials -> out. Removes 1M 32-way-contended
// global atomics and the out memset.

typedef __attribute__((ext_vector_type(8))) short short8;   // 8 bf16 (4 VGPRs)
typedef __attribute__((ext_vector_type(4))) float f32x4;    // MFMA acc

#define M_TOTAL 65536
#define KDIM    1024

// pack two fp32 -> two bf16 (round-half-up) in one dword: 2 adds + 1 v_perm
static __device__ inline unsigned int pk2h(float a, float b) {
    unsigned int ua = __builtin_bit_cast(unsigned int, a) + 0x8000u;
    unsigned int ub = __builtin_bit_cast(unsigned int, b) + 0x8000u;
    return __builtin_amdgcn_perm(ub, ua, 0x07060302u);
}

static __device__ inline uint4 pkvec(float4 f0, float4 f1) {
    uint4 pv;
    pv.x = pk2h(f0.x, f0.y);
    pv.y = pk2h(f0.z, f0.w);
    pv.z = pk2h(f1.x, f1.y);
    pv.w = pk2h(f1.z, f1.w);
    return pv;
}

// ---- w1 [d=k][e=n] fp32 -> fragment-linear bf16 image ----
// frag index = kt*64 + nt  (kt = k/32 in 0..31, nt = n/16 in 0..63)
// within frag: lane l, elem j = w1[kt*32 + (l>>4)*8 + j][nt*16 + (l&15)]
// -> 1 KiB per frag, each lane's 8 bf16 contiguous (one dwordx4 per load).
__global__ __launch_bounds__(64) void pack_w1(const float* __restrict__ w1,
                                              unsigned short* __restrict__ w1p) {
    const int nt = blockIdx.x;       // 0..63
    const int kt = blockIdx.y;       // 0..31
    const int l  = threadIdx.x;      // 0..63
    const int n  = nt * 16 + (l & 15);
    const int kb = kt * 32 + (l >> 4) * 8;
    const float* s = w1 + (size_t)kb * 1024 + n;
    uint4 wv;
    wv.x = pk2h(s[0],    s[1024]);
    wv.y = pk2h(s[2048], s[3072]);
    wv.z = pk2h(s[4096], s[5120]);
    wv.w = pk2h(s[6144], s[7168]);
    *reinterpret_cast<uint4*>(w1p + (((size_t)(kt * 64 + nt)) << 9) + (l << 3)) = wv;
}

// ---- qq[b][e] += partial of b1+b2 + dec[b]@w2, split-k x4 ----
__global__ __launch_bounds__(256) void qq_kern(const float* __restrict__ dec,
                                               const float* __restrict__ w2,
                                               const float* __restrict__ b1,
                                               const float* __restrict__ b2,
                                               float* __restrict__ qq) {
    const int b = blockIdx.y;
    const int e = blockIdx.x * 256 + threadIdx.x;
    const int d0 = blockIdx.z * 256;
    const float* db = dec + b * 1024;
    float acc = (blockIdx.z == 0) ? (b1[e] + b2[e]) : 0.f;
#pragma unroll 8
    for (int d = d0; d < d0 + 256; d++)
        acc = fmaf(db[d], w2[d * 1024 + e], acc);
    atomicAdd(&qq[b * 1024 + e], acc);
}

// ---- fused GEMM: A chunked-dbuf in LDS, B streamed L2->regs ----
__global__ __launch_bounds__(512, 2) void score_gemm(const float* __restrict__ enc,
                                                     const unsigned short* __restrict__ w1p,
                                                     const float* __restrict__ qq,
                                                     const float* __restrict__ vvec,
                                                     float* __restrict__ scores) {
    __shared__ __align__(16) unsigned short As[2][64 * 256];   // 2 x 32 KiB

    const int m0 = blockIdx.x << 6;       // 64 m-rows per block, 1024 blocks
    const int b = m0 >> 11;
    const int tid = threadIdx.x;
    const int wid = tid >> 6;             // 0..7, n-strip = wid*128
    const int lane = tid & 63;
    const int quad = lane >> 4, lc = lane & 15;

    // staging geometry: thread -> row sr = tid>>3 (0..63), float-col base
    // sc8 = tid&7. Per 256-k chunk: 4 windows w at float col sc8*8 + w*64.
    // Window w (8 floats -> 8 bf16 = 16 B) stored at slot w*8 + (sc8^(sr&7)).
    const int sr  = tid >> 3;
    const int sc8 = tid & 7;
    const float* srcrow = enc + (size_t)(m0 + sr) * 1024 + (sc8 << 3);
    const int dstoff = (sr << 8) + ((sc8 ^ (sr & 7)) << 3);   // shorts, + w*64

    f32x4 acc[4][8];
#pragma unroll
    for (int mi = 0; mi < 4; mi++)
#pragma unroll
        for (int ni = 0; ni < 8; ni++)
            acc[mi][ni] = (f32x4){0.f, 0.f, 0.f, 0.f};

    // B fragment stream base for this wave: frags (kt*64 + wid*8 + ni)
    // short offset = kt*32768 + wid*4096 + ni*512 + lane*8
    const unsigned short* bb = w1p + ((size_t)wid << 12) + (lane << 3);

    short8 bA[8], bB[8];
#pragma unroll
    for (int ni = 0; ni < 8; ni++)
        bA[ni] = *reinterpret_cast<const short8*>(bb + ni * 512);   // kt = 0

    // ---- prologue: stage chunk 0 (exposed once; B prefetch above overlaps) ----
    {
        float4 f0 = *reinterpret_cast<const float4*>(srcrow);
        float4 f1 = *reinterpret_cast<const float4*>(srcrow + 4);
        float4 f2 = *reinterpret_cast<const float4*>(srcrow + 64);
        float4 f3 = *reinterpret_cast<const float4*>(srcrow + 68);
        *reinterpret_cast<uint4*>(&As[0][dstoff])      = pkvec(f0, f1);
        *reinterpret_cast<uint4*>(&As[0][dstoff + 64]) = pkvec(f2, f3);
        f0 = *reinterpret_cast<const float4*>(srcrow + 128);
        f1 = *reinterpret_cast<const float4*>(srcrow + 132);
        f2 = *reinterpret_cast<const float4*>(srcrow + 192);
        f3 = *reinterpret_cast<const float4*>(srcrow + 196);
        *reinterpret_cast<uint4*>(&As[0][dstoff + 128]) = pkvec(f0, f1);
        *reinterpret_cast<uint4*>(&As[0][dstoff + 192]) = pkvec(f2, f3);
    }
    __syncthreads();

    for (int c = 0; c < 4; ++c) {
        const unsigned short* Ar = As[c & 1];
        unsigned short* Aw = const_cast<unsigned short*>(As[(c & 1) ^ 1]);
        const int more = (c < 3);
        const float* snext = srcrow + ((c + 1) << 8);

        float4 fv0, fv1, fv2, fv3;
        if (more) {   // issue batch0 (windows 0,1) of chunk c+1 early
            fv0 = *reinterpret_cast<const float4*>(snext);
            fv1 = *reinterpret_cast<const float4*>(snext + 4);
            fv2 = *reinterpret_cast<const float4*>(snext + 64);
            fv3 = *reinterpret_cast<const float4*>(snext + 68);
        }

#pragma unroll
        for (int half = 0; half < 2; ++half) {
#pragma unroll
            for (int it = 0; it < 2; ++it) {
                const int lk = half * 4 + it * 2;    // local k32-step (even)
                const int kt = c * 8 + lk;           // global k32-step
                // prefetch kt+1 into bB
#pragma unroll
                for (int ni = 0; ni < 8; ni++)
                    bB[ni] = *reinterpret_cast<const short8*>(bb + (kt + 1) * 32768 + ni * 512);

                short8 af[4];
                {
                    const int cc = lk * 4 + quad;
                    const int off = ((cc & ~7) | ((cc ^ lc) & 7)) << 3;
#pragma unroll
                    for (int mi = 0; mi < 4; mi++)
                        af[mi] = *reinterpret_cast<const short8*>(&Ar[((mi * 16 + lc) << 8) + off]);
                }
                __builtin_amdgcn_s_setprio(1);
#pragma unroll
                for (int mi = 0; mi < 4; mi++)
#pragma unroll
                    for (int ni = 0; ni < 8; ni++)
                        acc[mi][ni] = __builtin_amdgcn_mfma_f32_16x16x32_bf16(af[mi], bA[ni], acc[mi][ni], 0, 0, 0);
                __builtin_amdgcn_s_setprio(0);

                // prefetch kt+2 into bA
                if (kt < 30) {
#pragma unroll
                    for (int ni = 0; ni < 8; ni++)
                        bA[ni] = *reinterpret_cast<const short8*>(bb + (kt + 2) * 32768 + ni * 512);
                }
                {
                    const int cc = (lk + 1) * 4 + quad;
                    const int off = ((cc & ~7) | ((cc ^ lc) & 7)) << 3;
#pragma unroll
                    for (int mi = 0; mi < 4; mi++)
                        af[mi] = *reinterpret_cast<const short8*>(&Ar[((mi * 16 + lc) << 8) + off]);
                }
                __builtin_amdgcn_s_setprio(1);
#pragma unroll
                for (int mi = 0; mi < 4; mi++)
#pragma unroll
                    for (int ni = 0; ni < 8; ni++)
                        acc[mi][ni] = __builtin_amdgcn_mfma_f32_16x16x32_bf16(af[mi], bB[ni], acc[mi][ni], 0, 0, 0);
                __builtin_amdgcn_s_setprio(0);
            }

            if (more) {
                if (half == 0) {
                    // write batch0, then issue batch1 (windows 2,3)
                    *reinterpret_cast<uint4*>(&Aw[dstoff])      = pkvec(fv0, fv1);
                    *reinterpret_cast<uint4*>(&Aw[dstoff + 64]) = pkvec(fv2, fv3);
                    fv0 = *reinterpret_cast<const float4*>(snext + 128);
                    fv1 = *reinterpret_cast<const float4*>(snext + 132);
                    fv2 = *reinterpret_cast<const float4*>(snext + 192);
                    fv3 = *reinterpret_cast<const float4*>(snext + 196);
                } else {
                    *reinterpret_cast<uint4*>(&Aw[dstoff + 128]) = pkvec(fv0, fv1);
                    *reinterpret_cast<uint4*>(&Aw[dstoff + 192]) = pkvec(fv2, fv3);
                }
            }
        }
        __syncthreads();   // chunk boundary: writes visible, reads of Ar done
    }

    // ---- epilogue: tanh(C + qq)*v, reduce over this wave's 128 n ----
    // acc[mi][ni][r] = C[m = mi*16 + quad*4 + r][n = wid*128 + ni*16 + lc]
    const float* qb = qq + (b << 10) + (wid << 7) + lc;
    const float* vb = vvec + (wid << 7) + lc;
    float qn[8], vn[8];
#pragma unroll
    for (int ni = 0; ni < 8; ni++) {
        qn[ni] = qb[ni << 4];
        vn[ni] = vb[ni << 4];
    }
    float red[16];
#pragma unroll
    for (int mi = 0; mi < 4; mi++) {
#pragma unroll
        for (int r = 0; r < 4; r++) {
            float ssum = 0.f;
#pragma unroll
            for (int ni = 0; ni < 8; ni++) {
                float x = acc[mi][ni][r] + qn[ni];
                float e = __expf(2.0f * x);          // overflow-safe tanh
                float th = 1.0f - 2.0f / (e + 1.0f);
                ssum = fmaf(th, vn[ni], ssum);
            }
            float t = ssum;
            t += __shfl_xor(t, 1);
            t += __shfl_xor(t, 2);
            t += __shfl_xor(t, 4);
            t += __shfl_xor(t, 8);
            red[mi * 4 + r] = t;
        }
    }
    float myv = red[0];
#pragma unroll
    for (int i = 1; i < 16; i++)
        if (lc == i) myv = red[i];
    // lane (quad,lc) owns m = (lc>>2)*16 + quad*4 + (lc&3); 8 waves atomic-add
    atomicAdd(scores + m0 + (lc >> 2) * 16 + quad * 4 + (lc & 3), myv);
}

// ---- softmax over s (2048) per batch ----
__global__ __launch_bounds__(256) void softmax_kern(const float* __restrict__ scores,
                                                    float* __restrict__ attn) {
    const int b = blockIdx.x;
    const int tid = threadIdx.x;
    const int wid = tid >> 6, lane = tid & 63;
    const float* s = scores + b * 2048;
    float x[8];
    float m = -1e30f;
#pragma unroll
    for (int i = 0; i < 8; i++) {
        x[i] = s[tid + i * 256];
        m = fmaxf(m, x[i]);
    }
    for (int off = 1; off < 64; off <<= 1) m = fmaxf(m, __shfl_xor(m, off));
    __shared__ float redm[4];
    if (lane == 0) redm[wid] = m;
    __syncthreads();
    m = fmaxf(fmaxf(redm[0], redm[1]), fmaxf(redm[2], redm[3]));
    float sum = 0.f;
#pragma unroll
    for (int i = 0; i < 8; i++) {
        x[i] = __expf(x[i] - m);
        sum += x[i];
    }
    for (int off = 1; off < 64; off <<= 1) sum += __shfl_xor(sum, off);
    __shared__ float reds[4];
    if (lane == 0) reds[wid] = sum;
    __syncthreads();
    sum = reds[0] + reds[1] + reds[2] + reds[3];
    const float inv = 1.0f / sum;
#pragma unroll
    for (int i = 0; i < 8; i++) attn[b * 2048 + tid + i * 256] = x[i] * inv;
}

// ---- ctx partials: part[sc][b][e] = sum_{s in chunk sc} attn*enc, no atomics ----
__global__ __launch_bounds__(256) void ctx_part(const float* __restrict__ attn,
                                                const float* __restrict__ enc,
                                                float* __restrict__ part) {
    const int b = blockIdx.y;
    const int sc = blockIdx.x;    // 32 chunks x 64 s
    const int tid = threadIdx.x;
    const float* ab = attn + b * 2048 + sc * 64;
    const float* eb = enc + ((size_t)b * 2048 + sc * 64) * 1024 + tid * 4;
    float4 acc = {0.f, 0.f, 0.f, 0.f};
#pragma unroll 16
    for (int s = 0; s < 64; s++) {
        float w = ab[s];
        float4 ev = *reinterpret_cast<const float4*>(eb + (size_t)s * 1024);
        acc.x = fmaf(w, ev.x, acc.x);
        acc.y = fmaf(w, ev.y, acc.y);
        acc.z = fmaf(w, ev.z, acc.z);
        acc.w = fmaf(w, ev.w, acc.w);
    }
    *reinterpret_cast<float4*>(part + (((size_t)(sc * 32 + b)) << 10) + tid * 4) = acc;
}

// ---- out[b][e] = sum_sc part[sc][b][e] ----
__global__ __launch_bounds__(256) void ctx_reduce(const float* __restrict__ part,
                                                  float* __restrict__ out) {
    const int b = blockIdx.x;
    const int tid = threadIdx.x;
    const float* p = part + ((size_t)b << 10) + tid * 4;
    float4 acc = {0.f, 0.f, 0.f, 0.f};
#pragma unroll
    for (int sc = 0; sc < 32; sc++) {
        float4 v = *reinterpret_cast<const float4*>(p + ((size_t)sc << 15));
        acc.x += v.x; acc.y += v.y; acc.z += v.z; acc.w += v.w;
    }
    *reinterpret_cast<float4*>(out + b * 1024 + tid * 4) = acc;
}

extern "C" void kernel_launch(void* const* d_in, const int* in_sizes, int n_in,
                              void* d_out, int out_size, void* d_ws, size_t ws_size,
                              hipStream_t stream) {
    const float* enc = (const float*)d_in[0];  // 32*2048*1024
    const float* dec = (const float*)d_in[1];  // 32*1*1024
    const float* w1  = (const float*)d_in[2];  // 1024*1024
    const float* b1  = (const float*)d_in[3];  // 1024
    const float* w2  = (const float*)d_in[4];  // 1024*1024
    const float* b2  = (const float*)d_in[5];  // 1024
    const float* v   = (const float*)d_in[6];  // 1024
    // d_in[7] = bv, softmax-invariant, unused
    float* out = (float*)d_out;                // 32*1024

    char* ws = (char*)d_ws;
    unsigned short* w1p = (unsigned short*)ws;                 // 2 MB
    float* qq     = (float*)(ws + (2u << 20));                 // 128 KB
    float* scores = (float*)(ws + (2u << 20) + (128u << 10));  // 256 KB
    float* attn   = scores + M_TOTAL;                          // 256 KB
    float* part   = attn + M_TOTAL;                            // 4 MB
    // total ws need: ~6.65 MB

    hipMemsetAsync(qq, 0, (128u << 10) + M_TOTAL * sizeof(float), stream);

    pack_w1<<<dim3(64, 32), 64, 0, stream>>>(w1, w1p);
    qq_kern<<<dim3(4, 32, 4), 256, 0, stream>>>(dec, w2, b1, b2, qq);
    score_gemm<<<1024, 512, 0, stream>>>(enc, w1p, qq, v, scores);
    softmax_kern<<<32, 256, 0, stream>>>(scores, attn);
    ctx_part<<<dim3(32, 32), 256, 0, stream>>>(attn, enc, part);
    ctx_reduce<<<32, 256, 0, stream>>>(part, out);
}